// Round 3
// baseline (341.902 us; speedup 1.0000x reference)
//
#include <hip/hip_runtime.h>
#include <hip/hip_bf16.h>

#define NPTS 262144
#define NC 64
#define NK 27

typedef __attribute__((ext_vector_type(8))) short bf16x8;
typedef __attribute__((ext_vector_type(4))) float f32x4;

__device__ __forceinline__ float bflo(unsigned u) { return __uint_as_float(u << 16); }
__device__ __forceinline__ float bfhi(unsigned u) { return __uint_as_float(u & 0xffff0000u); }

__device__ __forceinline__ unsigned cvtpk(float lo, float hi) {
    unsigned r;
    asm("v_cvt_pk_bf16_f32 %0, %1, %2" : "=v"(r) : "v"(lo), "v"(hi));
    return r;
}

union BF { unsigned u[4]; bf16x8 v; };

// ---- Permuted bx storage layout -------------------------------------------
// ushort position p in a row maps to channel: chan(p) = ((p>>1)&15) + ((p&1)<<4) + (p&32)
// i.e. dword d (d<16) packs channels (d, d+16); dword 16+d packs (d+32, d+48).
// Lets gemm lanes emit packed dword stores (full 64B wave segments) and dwconv
// gather aligned uint4s; dwconv permutes dw weights at LDS load to compensate.

// Kernel A (MFMA): bx[r][perm] = bf16(sum_j feat[r][j]*W[j][c] + b1[c]).
__global__ __launch_bounds__(256) void gemm_mfma(const float* __restrict__ feat,
                                                 const float* __restrict__ W,
                                                 const float* __restrict__ b1,
                                                 ushort* __restrict__ bx) {
    __shared__ float Ws[NC * NC];
    __shared__ float b1S[NC];
    int t = threadIdx.x;
#pragma unroll
    for (int i = 0; i < 4; ++i)
        ((float4*)Ws)[t + i * 256] = ((const float4*)W)[t + i * 256];
    if (t < NC) b1S[t] = b1[t];
    __syncthreads();

    int lane = t & 63;
    int col = lane & 15;
    int kg = lane >> 4;
    int wid = blockIdx.x * 4 + (t >> 6);      // 4096 waves
    const int NWAVES = 1024 * 4;
    const int NTILES = NPTS / 16;             // 16384

    // B fragments (2 k-steps x 4 col-tiles) built once, held in regs.
    BF Bf[2][4];
#pragma unroll
    for (int ks = 0; ks < 2; ++ks)
#pragma unroll
        for (int ct = 0; ct < 4; ++ct)
#pragma unroll
            for (int r = 0; r < 4; ++r) {
                float lo = Ws[(ks * 32 + kg * 8 + 2 * r) * NC + ct * 16 + col];
                float hi = Ws[(ks * 32 + kg * 8 + 2 * r + 1) * NC + ct * 16 + col];
                Bf[ks][ct].u[r] = cvtpk(lo, hi);
            }
    float bias[4];
#pragma unroll
    for (int ct = 0; ct < 4; ++ct) bias[ct] = b1S[ct * 16 + col];

    for (int tile = wid; tile < NTILES; tile += NWAVES) {
        long r0 = (long)tile * 16;
        const float* ap = feat + (r0 + col) * NC + kg * 8;
        float4 a0 = *(const float4*)(ap);
        float4 a1 = *(const float4*)(ap + 4);
        float4 a2 = *(const float4*)(ap + 32);
        float4 a3 = *(const float4*)(ap + 36);
        BF A0, A1;
        A0.u[0] = cvtpk(a0.x, a0.y); A0.u[1] = cvtpk(a0.z, a0.w);
        A0.u[2] = cvtpk(a1.x, a1.y); A0.u[3] = cvtpk(a1.z, a1.w);
        A1.u[0] = cvtpk(a2.x, a2.y); A1.u[1] = cvtpk(a2.z, a2.w);
        A1.u[2] = cvtpk(a3.x, a3.y); A1.u[3] = cvtpk(a3.z, a3.w);

        f32x4 acc[4];
#pragma unroll
        for (int ct = 0; ct < 4; ++ct) {
            acc[ct] = (f32x4){bias[ct], bias[ct], bias[ct], bias[ct]};
            acc[ct] = __builtin_amdgcn_mfma_f32_16x16x32_bf16(A0.v, Bf[0][ct].v, acc[ct], 0, 0, 0);
            acc[ct] = __builtin_amdgcn_mfma_f32_16x16x32_bf16(A1.v, Bf[1][ct].v, acc[ct], 0, 0, 0);
        }

        // Packed permuted store: dword col = (ct0,ct1), dword 16+col = (ct2,ct3).
#pragma unroll
        for (int i = 0; i < 4; ++i) {
            uint* bu = (uint*)(bx + (r0 + kg * 4 + i) * NC);
            bu[col]      = cvtpk(acc[0][i], acc[1][i]);
            bu[16 + col] = cvtpk(acc[2][i], acc[3][i]);
        }
    }
}

// Kernel B: out[r][c] = feat[r][c] + b2[c] + sum_k dw[k][c]*bx[nb[r][k]][c]
// 8 lanes/row, 32 rows/block. nb staged in LDS; 3 batches of 9 predicated
// gathers kept in registers (structural MLP); no divergent branches.
__global__ __launch_bounds__(256) void dwconv(const float* __restrict__ feat,
                                              const int* __restrict__ nb,
                                              const float* __restrict__ b2,
                                              const float* __restrict__ dw,
                                              const ushort* __restrict__ bx,
                                              float* __restrict__ out) {
    __shared__ float dwS[NK * NC];   // permuted to bx storage order
    __shared__ float b2S[NC];
    __shared__ int nbS[32 * NK];
    int t = threadIdx.x;
    for (int i = t; i < NK * NC; i += 256) {
        int p = i & 63;
        int ch = ((p >> 1) & 15) + ((p & 1) << 4) + (p & 32);
        dwS[i] = dw[(i & ~63) + ch];
    }
    if (t < NC) b2S[t] = b2[t];

    // bijective chunked XCD swizzle (gridDim.x = 8192, %8 == 0)
    int b = blockIdx.x;
    int chunk = gridDim.x >> 3;
    int sb = (b & 7) * chunk + (b >> 3);

    // stage this block's 32x27 neighbor tile (864 ints = 216 uint4)
    const uint4* nbsrc = (const uint4*)(nb + (size_t)sb * 32 * NK);
    if (t < 216) ((uint4*)nbS)[t] = nbsrc[t];
    __syncthreads();

    int r = t >> 3;
    int q = t & 7;
    long row = (long)sb * 32 + r;
    int lo_c0 = (q < 4) ? 4 * q : 16 + 4 * q;   // original-channel base of low half
    int hi_c0 = lo_c0 + 16;

    float4 flo = *(const float4*)(feat + row * NC + lo_c0);
    float4 fhi = *(const float4*)(feat + row * NC + hi_c0);

    float acc[8] = {0.f, 0.f, 0.f, 0.f, 0.f, 0.f, 0.f, 0.f};

    const int* nrow = nbS + r * NK;
#pragma unroll
    for (int batch = 0; batch < 3; ++batch) {
        int idxv[9];
        uint4 g[9];
#pragma unroll
        for (int j = 0; j < 9; ++j) idxv[j] = nrow[batch * 9 + j];
#pragma unroll
        for (int j = 0; j < 9; ++j) {
            int id = idxv[j];
            int ids = (id >= 0) ? id : 0;     // row 0 stays L1-hot
            g[j] = *(const uint4*)(bx + (size_t)ids * NC + q * 8);
        }
#pragma unroll
        for (int j = 0; j < 9; ++j) {
            int k = batch * 9 + j;
            uint4 gg = g[j];
            if (idxv[j] < 0) { gg.x = 0u; gg.y = 0u; gg.z = 0u; gg.w = 0u; }
            float4 w0 = *(const float4*)(dwS + k * NC + q * 8);
            float4 w1 = *(const float4*)(dwS + k * NC + q * 8 + 4);
            acc[0] += bflo(gg.x) * w0.x;
            acc[1] += bfhi(gg.x) * w0.y;
            acc[2] += bflo(gg.y) * w0.z;
            acc[3] += bfhi(gg.y) * w0.w;
            acc[4] += bflo(gg.z) * w1.x;
            acc[5] += bfhi(gg.z) * w1.y;
            acc[6] += bflo(gg.w) * w1.z;
            acc[7] += bfhi(gg.w) * w1.w;
        }
    }

    // acc[2i+h] holds storage pos 8q+2i+h == channel (lo_c0+i) for h=0, (hi_c0+i) for h=1
    float4 olo = make_float4(acc[0] + flo.x + b2S[lo_c0 + 0],
                             acc[2] + flo.y + b2S[lo_c0 + 1],
                             acc[4] + flo.z + b2S[lo_c0 + 2],
                             acc[6] + flo.w + b2S[lo_c0 + 3]);
    float4 ohi = make_float4(acc[1] + fhi.x + b2S[hi_c0 + 0],
                             acc[3] + fhi.y + b2S[hi_c0 + 1],
                             acc[5] + fhi.z + b2S[hi_c0 + 2],
                             acc[7] + fhi.w + b2S[hi_c0 + 3]);
    *(float4*)(out + row * NC + lo_c0) = olo;
    *(float4*)(out + row * NC + hi_c0) = ohi;
}

extern "C" void kernel_launch(void* const* d_in, const int* in_sizes, int n_in,
                              void* d_out, int out_size, void* d_ws, size_t ws_size,
                              hipStream_t stream) {
    const float* feat = (const float*)d_in[0];
    const int*   nb   = (const int*)d_in[1];
    const float* W    = (const float*)d_in[2];
    const float* b1   = (const float*)d_in[3];
    const float* b2   = (const float*)d_in[4];
    const float* dw   = (const float*)d_in[5];
    float* out = (float*)d_out;
    ushort* bx = (ushort*)d_ws;   // N*C bf16 (permuted channel order) = 33.5 MB

    gemm_mfma<<<1024, 256, 0, stream>>>(feat, W, b1, bx);
    dwconv<<<NPTS / 32, 256, 0, stream>>>(feat, nb, b2, dw, bx, out);
}

// Round 6
// 205.265 us; speedup vs baseline: 1.6657x; 1.6657x over previous
//
#include <hip/hip_runtime.h>
#include <hip/hip_bf16.h>

#define NPTS 262144
#define NC 64
#define NK 27

typedef __attribute__((ext_vector_type(8))) short bf16x8;
typedef __attribute__((ext_vector_type(4))) float f32x4;

__device__ __forceinline__ float bflo(unsigned u) { return __uint_as_float(u << 16); }
__device__ __forceinline__ float bfhi(unsigned u) { return __uint_as_float(u & 0xffff0000u); }

__device__ __forceinline__ unsigned cvtpk(float lo, float hi) {
    unsigned r;
    asm("v_cvt_pk_bf16_f32 %0, %1, %2" : "=v"(r) : "v"(lo), "v"(hi));
    return r;
}

union BF { unsigned u[4]; bf16x8 v; };

// ---- Permuted bx storage layout -------------------------------------------
// ushort position p in a row maps to channel: chan(p) = ((p>>1)&15) + ((p&1)<<4) + (p&32)
// dword d (d<16) packs channels (d, d+16); dword 16+d packs (d+32, d+48).
// gemm emits packed dword stores (full 64B wave segments); dwconv compensates
// by permuting dw at LDS-load time.

// Kernel A (MFMA): bx[r][perm] = bf16(sum_j feat[r][j]*W[j][c] + b1[c]).
__global__ __launch_bounds__(256) void gemm_mfma(const float* __restrict__ feat,
                                                 const float* __restrict__ W,
                                                 const float* __restrict__ b1,
                                                 ushort* __restrict__ bx) {
    __shared__ float Ws[NC * NC];
    __shared__ float b1S[NC];
    int t = threadIdx.x;
#pragma unroll
    for (int i = 0; i < 4; ++i)
        ((float4*)Ws)[t + i * 256] = ((const float4*)W)[t + i * 256];
    if (t < NC) b1S[t] = b1[t];
    __syncthreads();

    int lane = t & 63;
    int col = lane & 15;
    int kg = lane >> 4;
    int wid = blockIdx.x * 4 + (t >> 6);      // 8192 waves
    const int NWAVES = 2048 * 4;
    const int NTILES = NPTS / 16;             // 16384

    // B fragments (2 k-steps x 4 col-tiles) built once, held in regs.
    BF Bf[2][4];
#pragma unroll
    for (int ks = 0; ks < 2; ++ks)
#pragma unroll
        for (int ct = 0; ct < 4; ++ct)
#pragma unroll
            for (int r = 0; r < 4; ++r) {
                float lo = Ws[(ks * 32 + kg * 8 + 2 * r) * NC + ct * 16 + col];
                float hi = Ws[(ks * 32 + kg * 8 + 2 * r + 1) * NC + ct * 16 + col];
                Bf[ks][ct].u[r] = cvtpk(lo, hi);
            }
    float bias[4];
#pragma unroll
    for (int ct = 0; ct < 4; ++ct) bias[ct] = b1S[ct * 16 + col];

    for (int tile = wid; tile < NTILES; tile += NWAVES) {
        long r0 = (long)tile * 16;
        const float* ap = feat + (r0 + col) * NC + kg * 8;
        float4 a0 = *(const float4*)(ap);
        float4 a1 = *(const float4*)(ap + 4);
        float4 a2 = *(const float4*)(ap + 32);
        float4 a3 = *(const float4*)(ap + 36);
        BF A0, A1;
        A0.u[0] = cvtpk(a0.x, a0.y); A0.u[1] = cvtpk(a0.z, a0.w);
        A0.u[2] = cvtpk(a1.x, a1.y); A0.u[3] = cvtpk(a1.z, a1.w);
        A1.u[0] = cvtpk(a2.x, a2.y); A1.u[1] = cvtpk(a2.z, a2.w);
        A1.u[2] = cvtpk(a3.x, a3.y); A1.u[3] = cvtpk(a3.z, a3.w);

        f32x4 acc[4];
#pragma unroll
        for (int ct = 0; ct < 4; ++ct) {
            acc[ct] = (f32x4){bias[ct], bias[ct], bias[ct], bias[ct]};
            acc[ct] = __builtin_amdgcn_mfma_f32_16x16x32_bf16(A0.v, Bf[0][ct].v, acc[ct], 0, 0, 0);
            acc[ct] = __builtin_amdgcn_mfma_f32_16x16x32_bf16(A1.v, Bf[1][ct].v, acc[ct], 0, 0, 0);
        }

        // Packed permuted store: dword col = (ct0,ct1), dword 16+col = (ct2,ct3).
#pragma unroll
        for (int i = 0; i < 4; ++i) {
            uint* bu = (uint*)(bx + (r0 + kg * 4 + i) * NC);
            bu[col]      = cvtpk(acc[0][i], acc[1][i]);
            bu[16 + col] = cvtpk(acc[2][i], acc[3][i]);
        }
    }
}

// Kernel B: out[r][c] = feat[r][c] + b2[c] + sum_k dw[k][c]*bx[nb[r][k]][c]
// 8 lanes/row, 32 rows/block. Straight-line fully-unrolled k-loop, branch-free;
// invalid k redirects the weight read to a zero row (validity uniform per row).
// __launch_bounds__(256,8) caps VGPR at 64 -> 8 blocks/CU, scheduler pipelines
// gathers ~4 deep inside that budget.
__global__ __launch_bounds__(256, 8) void dwconv(const float* __restrict__ feat,
                                                 const int* __restrict__ nb,
                                                 const float* __restrict__ b2,
                                                 const float* __restrict__ dw,
                                                 const ushort* __restrict__ bx,
                                                 float* __restrict__ out) {
    __shared__ float dwS[28 * NC];   // permuted to bx storage order; row 27 = zeros
    __shared__ float b2S[NC];
    __shared__ int nbS[32 * NK];
    int t = threadIdx.x;
    for (int i = t; i < NK * NC; i += 256) {
        int p = i & 63;
        int ch = ((p >> 1) & 15) + ((p & 1) << 4) + (p & 32);
        dwS[i] = dw[(i & ~63) + ch];
    }
    if (t < NC) dwS[27 * NC + t] = 0.f;
    if (t < NC) b2S[t] = b2[t];

    // bijective chunked XCD swizzle (gridDim.x = 8192, %8 == 0)
    int b = blockIdx.x;
    int chunk = gridDim.x >> 3;
    int sb = (b & 7) * chunk + (b >> 3);

    // stage this block's 32x27 neighbor tile (864 ints = 216 uint4)
    const uint4* nbsrc = (const uint4*)(nb + (size_t)sb * 32 * NK);
    if (t < 216) ((uint4*)nbS)[t] = nbsrc[t];
    __syncthreads();

    int r = t >> 3;
    int q = t & 7;
    long row = (long)sb * 32 + r;
    int lo_c0 = (q < 4) ? 4 * q : 16 + 4 * q;   // original-channel base of low half
    int hi_c0 = lo_c0 + 16;

    float4 flo = *(const float4*)(feat + row * NC + lo_c0);
    float4 fhi = *(const float4*)(feat + row * NC + hi_c0);

    float acc[8] = {0.f, 0.f, 0.f, 0.f, 0.f, 0.f, 0.f, 0.f};

    const int* nrow = nbS + r * NK;
    const ushort* bq = bx + q * 8;
    const float* wq = dwS + q * 8;

#pragma unroll
    for (int k = 0; k < NK; ++k) {
        int id = nrow[k];
        int ids = max(id, 0);                      // row 0 stays hot
        int krow = (id < 0) ? 27 : k;              // zero-weight row if invalid
        uint4 g = *(const uint4*)(bq + (size_t)ids * NC);
        float4 w0 = *(const float4*)(wq + krow * NC);
        float4 w1 = *(const float4*)(wq + krow * NC + 4);
        acc[0] += bflo(g.x) * w0.x;
        acc[1] += bfhi(g.x) * w0.y;
        acc[2] += bflo(g.y) * w0.z;
        acc[3] += bfhi(g.y) * w0.w;
        acc[4] += bflo(g.z) * w1.x;
        acc[5] += bfhi(g.z) * w1.y;
        acc[6] += bflo(g.w) * w1.z;
        acc[7] += bfhi(g.w) * w1.w;
    }

    // acc[2i+h]: storage pos 8q+2i+h == channel (lo_c0+i) h=0, (hi_c0+i) h=1
    float4 olo = make_float4(acc[0] + flo.x + b2S[lo_c0 + 0],
                             acc[2] + flo.y + b2S[lo_c0 + 1],
                             acc[4] + flo.z + b2S[lo_c0 + 2],
                             acc[6] + flo.w + b2S[lo_c0 + 3]);
    float4 ohi = make_float4(acc[1] + fhi.x + b2S[hi_c0 + 0],
                             acc[3] + fhi.y + b2S[hi_c0 + 1],
                             acc[5] + fhi.z + b2S[hi_c0 + 2],
                             acc[7] + fhi.w + b2S[hi_c0 + 3]);
    *(float4*)(out + row * NC + lo_c0) = olo;
    *(float4*)(out + row * NC + hi_c0) = ohi;
}

extern "C" void kernel_launch(void* const* d_in, const int* in_sizes, int n_in,
                              void* d_out, int out_size, void* d_ws, size_t ws_size,
                              hipStream_t stream) {
    const float* feat = (const float*)d_in[0];
    const int*   nb   = (const int*)d_in[1];
    const float* W    = (const float*)d_in[2];
    const float* b1   = (const float*)d_in[3];
    const float* b2   = (const float*)d_in[4];
    const float* dw   = (const float*)d_in[5];
    float* out = (float*)d_out;
    ushort* bx = (ushort*)d_ws;   // N*C bf16 (permuted channel order) = 33.5 MB

    gemm_mfma<<<2048, 256, 0, stream>>>(feat, W, b1, bx);
    dwconv<<<NPTS / 32, 256, 0, stream>>>(feat, nb, b2, dw, bx, out);
}

// Round 7
// 204.784 us; speedup vs baseline: 1.6696x; 1.0024x over previous
//
#include <hip/hip_runtime.h>
#include <hip/hip_bf16.h>

#define NPTS 262144
#define NC 64
#define NK 27
#define RPB 128          // rows per block (dwconv)
#define NBS 132          // padded int stride of transposed nbT rows

typedef __attribute__((ext_vector_type(8))) short bf16x8;
typedef __attribute__((ext_vector_type(4))) float f32x4;
typedef __attribute__((ext_vector_type(2))) float f32x2;

__device__ __forceinline__ unsigned cvtpk(float lo, float hi) {
    unsigned r;
    asm("v_cvt_pk_bf16_f32 %0, %1, %2" : "=v"(r) : "v"(lo), "v"(hi));
    return r;
}
__device__ __forceinline__ f32x2 up2(unsigned u) {
    f32x2 r;
    r.x = __uint_as_float(u << 16);
    r.y = __uint_as_float(u & 0xffff0000u);
    return r;
}

union BF { unsigned u[4]; bf16x8 v; };

// ---- Permuted bx storage layout -------------------------------------------
// ushort position p in a row maps to channel chan(p) = ((p>>1)&15) + ((p&1)<<4) + (p&32).
// dword d (d<16) packs channels (d, d+16); dword 16+d packs (d+32, d+48).

// Kernel A (MFMA): bx[r][perm] = bf16(feat[r]@W + b1). Also zeroes sentinel row.
__global__ __launch_bounds__(256) void gemm_mfma(const float* __restrict__ feat,
                                                 const float* __restrict__ W,
                                                 const float* __restrict__ b1,
                                                 ushort* __restrict__ bx,
                                                 uint* __restrict__ zrow) {
    __shared__ float Ws[NC * NC];
    __shared__ float b1S[NC];
    int t = threadIdx.x;
    if (zrow && blockIdx.x == 0 && t < 32) zrow[t] = 0u;   // 128B sentinel row
#pragma unroll
    for (int i = 0; i < 4; ++i)
        ((float4*)Ws)[t + i * 256] = ((const float4*)W)[t + i * 256];
    if (t < NC) b1S[t] = b1[t];
    __syncthreads();

    int lane = t & 63;
    int col = lane & 15;
    int kg = lane >> 4;
    int wid = blockIdx.x * 4 + (t >> 6);
    const int NWAVES = 2048 * 4;
    const int NTILES = NPTS / 16;

    BF Bf[2][4];
#pragma unroll
    for (int ks = 0; ks < 2; ++ks)
#pragma unroll
        for (int ct = 0; ct < 4; ++ct)
#pragma unroll
            for (int r = 0; r < 4; ++r) {
                float lo = Ws[(ks * 32 + kg * 8 + 2 * r) * NC + ct * 16 + col];
                float hi = Ws[(ks * 32 + kg * 8 + 2 * r + 1) * NC + ct * 16 + col];
                Bf[ks][ct].u[r] = cvtpk(lo, hi);
            }
    float bias[4];
#pragma unroll
    for (int ct = 0; ct < 4; ++ct) bias[ct] = b1S[ct * 16 + col];

    for (int tile = wid; tile < NTILES; tile += NWAVES) {
        long r0 = (long)tile * 16;
        const float* ap = feat + (r0 + col) * NC + kg * 8;
        float4 a0 = *(const float4*)(ap);
        float4 a1 = *(const float4*)(ap + 4);
        float4 a2 = *(const float4*)(ap + 32);
        float4 a3 = *(const float4*)(ap + 36);
        BF A0, A1;
        A0.u[0] = cvtpk(a0.x, a0.y); A0.u[1] = cvtpk(a0.z, a0.w);
        A0.u[2] = cvtpk(a1.x, a1.y); A0.u[3] = cvtpk(a1.z, a1.w);
        A1.u[0] = cvtpk(a2.x, a2.y); A1.u[1] = cvtpk(a2.z, a2.w);
        A1.u[2] = cvtpk(a3.x, a3.y); A1.u[3] = cvtpk(a3.z, a3.w);

        f32x4 acc[4];
#pragma unroll
        for (int ct = 0; ct < 4; ++ct) {
            acc[ct] = (f32x4){bias[ct], bias[ct], bias[ct], bias[ct]};
            acc[ct] = __builtin_amdgcn_mfma_f32_16x16x32_bf16(A0.v, Bf[0][ct].v, acc[ct], 0, 0, 0);
            acc[ct] = __builtin_amdgcn_mfma_f32_16x16x32_bf16(A1.v, Bf[1][ct].v, acc[ct], 0, 0, 0);
        }
#pragma unroll
        for (int i = 0; i < 4; ++i) {
            uint* bu = (uint*)(bx + (r0 + kg * 4 + i) * NC);
            bu[col]      = cvtpk(acc[0][i], acc[1][i]);
            bu[16 + col] = cvtpk(acc[2][i], acc[3][i]);
        }
    }
}

// Kernel B: k-outer, 4 rows x 8 channels per thread. Transposed+padded nbT in
// LDS (idx b128 per k serves 4 rows); weights broadcast at const offsets
// (conflict-free); validity via sentinel zero-row (SENT) or cndmask fallback.
template <bool SENT>
__global__ __launch_bounds__(256, 5) void dwconv(const float* __restrict__ feat,
                                                 const int* __restrict__ nb,
                                                 const float* __restrict__ b2,
                                                 const float* __restrict__ dw,
                                                 const ushort* __restrict__ bx,
                                                 float* __restrict__ out) {
    __shared__ int nbT[NK * NBS];
    __shared__ float dwS[NK * NC];   // permuted to bx storage order
    __shared__ float b2S[NC];
    int t = threadIdx.x;
    for (int i = t; i < NK * NC; i += 256) {
        int p = i & 63;
        int ch = ((p >> 1) & 15) + ((p & 1) << 4) + (p & 32);
        dwS[i] = dw[(i & ~63) + ch];
    }
    if (t < NC) b2S[t] = b2[t];

    // bijective chunked XCD swizzle (gridDim.x = 2048, %8 == 0)
    int b = blockIdx.x;
    int chunk = gridDim.x >> 3;
    int sb = (b & 7) * chunk + (b >> 3);

    // stage+transpose(+sanitize) this block's 128x27 neighbor tile
    const int* nsrc = nb + (size_t)sb * RPB * NK;
    for (int i = t; i < RPB * NK; i += 256) {
        int r = i / NK;
        int k = i - r * NK;
        int v = nsrc[i];
        if (SENT) v = (v < 0) ? NPTS : v;
        nbT[k * NBS + r] = v;
    }
    __syncthreads();

    int g = t >> 3;                    // row group 0..31
    int q = t & 7;                     // channel-quad 0..7
    long row0 = (long)sb * RPB + g * 4;
    unsigned qo = (unsigned)q << 4;    // byte offset within bx row

    f32x2 acc[4][4];
#pragma unroll
    for (int j = 0; j < 4; ++j)
#pragma unroll
        for (int i = 0; i < 4; ++i) acc[j][i] = (f32x2){0.f, 0.f};

    const char* bp = (const char*)bx;
    const int* nbase = nbT + g * 4;
    const f32x2* wbase = (const f32x2*)dwS + q * 4;

#pragma unroll 3
    for (int k = 0; k < NK; ++k) {
        int4 idx = *(const int4*)(nbase + k * NBS);
        int sx = idx.x, sy = idx.y, sz = idx.z, sw = idx.w;
        if (!SENT) { sx = max(sx, 0); sy = max(sy, 0); sz = max(sz, 0); sw = max(sw, 0); }
        uint4 g0 = *(const uint4*)(bp + (((unsigned)sx << 7) + qo));
        uint4 g1 = *(const uint4*)(bp + (((unsigned)sy << 7) + qo));
        uint4 g2 = *(const uint4*)(bp + (((unsigned)sz << 7) + qo));
        uint4 g3 = *(const uint4*)(bp + (((unsigned)sw << 7) + qo));
        if (!SENT) {
            unsigned m0 = idx.x >= 0 ? 0xffffffffu : 0u;
            unsigned m1 = idx.y >= 0 ? 0xffffffffu : 0u;
            unsigned m2 = idx.z >= 0 ? 0xffffffffu : 0u;
            unsigned m3 = idx.w >= 0 ? 0xffffffffu : 0u;
            g0.x &= m0; g0.y &= m0; g0.z &= m0; g0.w &= m0;
            g1.x &= m1; g1.y &= m1; g1.z &= m1; g1.w &= m1;
            g2.x &= m2; g2.y &= m2; g2.z &= m2; g2.w &= m2;
            g3.x &= m3; g3.y &= m3; g3.z &= m3; g3.w &= m3;
        }
        f32x2 w0 = wbase[k * 32 + 0];
        f32x2 w1 = wbase[k * 32 + 1];
        f32x2 w2 = wbase[k * 32 + 2];
        f32x2 w3 = wbase[k * 32 + 3];
        acc[0][0] += up2(g0.x) * w0; acc[0][1] += up2(g0.y) * w1;
        acc[0][2] += up2(g0.z) * w2; acc[0][3] += up2(g0.w) * w3;
        acc[1][0] += up2(g1.x) * w0; acc[1][1] += up2(g1.y) * w1;
        acc[1][2] += up2(g1.z) * w2; acc[1][3] += up2(g1.w) * w3;
        acc[2][0] += up2(g2.x) * w0; acc[2][1] += up2(g2.y) * w1;
        acc[2][2] += up2(g2.z) * w2; acc[2][3] += up2(g2.w) * w3;
        acc[3][0] += up2(g3.x) * w0; acc[3][1] += up2(g3.y) * w1;
        acc[3][2] += up2(g3.z) * w2; acc[3][3] += up2(g3.w) * w3;
    }

    int lo_c0 = (q < 4) ? 4 * q : 16 + 4 * q;
    int hi_c0 = lo_c0 + 16;
#pragma unroll
    for (int j = 0; j < 4; ++j) {
        long row = row0 + j;
        const float* fp = feat + row * NC;
        float4 flo = *(const float4*)(fp + lo_c0);
        float4 fhi = *(const float4*)(fp + hi_c0);
        float4 olo = make_float4(acc[j][0].x + flo.x + b2S[lo_c0 + 0],
                                 acc[j][1].x + flo.y + b2S[lo_c0 + 1],
                                 acc[j][2].x + flo.z + b2S[lo_c0 + 2],
                                 acc[j][3].x + flo.w + b2S[lo_c0 + 3]);
        float4 ohi = make_float4(acc[j][0].y + fhi.x + b2S[hi_c0 + 0],
                                 acc[j][1].y + fhi.y + b2S[hi_c0 + 1],
                                 acc[j][2].y + fhi.z + b2S[hi_c0 + 2],
                                 acc[j][3].y + fhi.w + b2S[hi_c0 + 3]);
        *(float4*)(out + row * NC + lo_c0) = olo;
        *(float4*)(out + row * NC + hi_c0) = ohi;
    }
}

extern "C" void kernel_launch(void* const* d_in, const int* in_sizes, int n_in,
                              void* d_out, int out_size, void* d_ws, size_t ws_size,
                              hipStream_t stream) {
    const float* feat = (const float*)d_in[0];
    const int*   nb   = (const int*)d_in[1];
    const float* W    = (const float*)d_in[2];
    const float* b1   = (const float*)d_in[3];
    const float* b2   = (const float*)d_in[4];
    const float* dw   = (const float*)d_in[5];
    float* out = (float*)d_out;
    ushort* bx = (ushort*)d_ws;   // (NPTS+1) rows x 64 bf16 (permuted), sentinel last

    bool sent = ws_size >= (size_t)(NPTS + 1) * NC * sizeof(ushort);
    uint* zrow = sent ? (uint*)(bx + (size_t)NPTS * NC) : nullptr;

    gemm_mfma<<<2048, 256, 0, stream>>>(feat, W, b1, bx, zrow);
    if (sent)
        dwconv<true><<<NPTS / RPB, 256, 0, stream>>>(feat, nb, b2, dw, bx, out);
    else
        dwconv<false><<<NPTS / RPB, 256, 0, stream>>>(feat, nb, b2, dw, bx, out);
}